// Round 7
// baseline (2452.186 us; speedup 1.0000x reference)
//
#include <hip/hip_runtime.h>
#include <hip/hip_bf16.h>

// RNN: T=512, B=256, D_IN=256, D_LAT=512, D_OUT=256
// d_out = [outputs (T*B*256 f32) | hidden_states (T*B*512 f32)]
//   1) pre-GEMM:  A = X @ Wx + bh  -> hidden region (in-place scratch)
//   2) scan: 64 blocks = 16 groups x 4 col-blocks, Wr pinned in VGPRs via inline-asm
//      loads (non-rematerializable). ZERO-FLAG exchange: validity in bf16 sign bits
//      (post-relu data is sign-clear), polarity alternates per slot reuse; readers
//      poll data directly. No store-drain, no flags => ~1 L3 RTT per step.
//   3) post-GEMM: Out = H @ Wo + bo

#define TT 512
#define BB 256
#define DIN 256
#define DLAT 512
#define DOUT 256

typedef short bf16x8 __attribute__((ext_vector_type(8)));
typedef int   i32x4  __attribute__((ext_vector_type(4)));
typedef float f32x4  __attribute__((ext_vector_type(4)));

__device__ __forceinline__ unsigned short f2bf(float f) {
  union { float f; unsigned u; } v; v.f = f;
  unsigned r = v.u + (((v.u >> 16) & 1u) + 0x7fffu);  // RNE
  return (unsigned short)(r >> 16);
}
__device__ __forceinline__ unsigned pack2(float a, float b) {
  return (unsigned)f2bf(a) | ((unsigned)f2bf(b) << 16);
}

// ---- raw L3-coherent (sc0 sc1) ops: bypass L1+L2, coherence point = L3 ----
__device__ __forceinline__ i32x4 load_b128_sc(const void* p) {
  i32x4 r;
  asm volatile("global_load_dwordx4 %0, %1, off sc0 sc1" : "=v"(r) : "v"(p) : "memory");
  return r;
}
__device__ __forceinline__ void store_b128_sc(void* p, i32x4 v) {
  asm volatile("global_store_dwordx4 %0, %1, off sc0 sc1" :: "v"(p), "v"(v) : "memory");
}
__device__ __forceinline__ void waitvm0() {
  asm volatile("s_waitcnt vmcnt(0)" ::: "memory");
  __builtin_amdgcn_sched_barrier(0);
}
// plain cached 16B load, but OPAQUE to the compiler (can't be rematerialized/sunk):
// used to pin the Wr weight fragments in VGPRs for the whole kernel.
__device__ __forceinline__ i32x4 load_b128_pin(const void* p) {
  i32x4 r;
  asm volatile("global_load_dwordx4 %0, %1, off" : "=v"(r) : "v"(p) : "memory");
  return r;
}

// ---------------- weight prep: f32 -> bf16, transposed [col][k], XOR-swizzled ----------------
__global__ __launch_bounds__(256) void prep_kernel(
    const float* __restrict__ Wh, const float* __restrict__ Wo,
    unsigned short* __restrict__ wx, unsigned short* __restrict__ wr,
    unsigned short* __restrict__ wo) {
  int id = blockIdx.x * 256 + threadIdx.x;  // 0..262143
  {  // Wr: [512][512] from Wh rows 256..767
    int k = id >> 9, col = id & 511;
    int s = col >> 7, c = col & 127;
    wr[(s << 16) + (((c << 9) | k) ^ ((c & 7) << 3))] = f2bf(Wh[(256 + k) * 512 + col]);
  }
  if (id < 131072) {  // Wx: [256][512] from Wh rows 0..255
    int k = id >> 9, col = id & 511;
    int s = col >> 7, c = col & 127;
    wx[(s << 15) + (((c << 8) | k) ^ ((c & 7) << 3))] = f2bf(Wh[id]);
  }
  if (id < 131072) {  // Wo: [512][256]
    int k = id >> 8, col = id & 255;
    int s = col >> 7, c = col & 127;
    wo[(s << 16) + (((c << 9) | k) ^ ((c & 7) << 3))] = f2bf(Wo[id]);
  }
}

// ---------------- generic GEMM + bias (unchanged) ----------------
template <int K, int NSTR, int SLBITS>
__global__ __launch_bounds__(256) void gemm_bias(
    const float* __restrict__ Xg, const unsigned short* __restrict__ Wp,
    const float* __restrict__ bias, float* __restrict__ Cg) {
  __shared__ unsigned short ldsW[128 * K];
  __shared__ unsigned short ldsA[128 * 64];
  const int tid = threadIdx.x;
  const int s = blockIdx.x & ((1 << SLBITS) - 1);
  const size_t r0 = (size_t)(blockIdx.x >> SLBITS) * 128;
  {
    const uint4* src = (const uint4*)(Wp + (size_t)s * 128 * K);
    uint4* dst = (uint4*)ldsW;
#pragma unroll
    for (int i = 0; i < (128 * K / 8) / 256; ++i) dst[tid + 256 * i] = src[tid + 256 * i];
  }
  const int lane = tid & 63, wid = tid >> 6;
  const int wm = wid >> 1, wn = wid & 1;
  const int cl = lane & 15, kh = lane >> 4;
  f32x4 acc[4][4];
#pragma unroll
  for (int nf = 0; nf < 4; ++nf) {
    float bv = bias[s * 128 + wn * 64 + nf * 16 + cl];
#pragma unroll
    for (int mf = 0; mf < 4; ++mf) { f32x4 t = {bv, bv, bv, bv}; acc[mf][nf] = t; }
  }
  __syncthreads();
  for (int k0 = 0; k0 < K; k0 += 64) {
#pragma unroll
    for (int i = 0; i < 8; ++i) {
      int g = tid + 256 * i;
      int row = g >> 4, kg = g & 15;
      const float4 v = *(const float4*)&Xg[(r0 + row) * K + (k0 + kg * 4)];
      int idx = (row * 64 + kg * 4) ^ ((row & 7) << 3);
      uint2 u; u.x = pack2(v.x, v.y); u.y = pack2(v.z, v.w);
      *(uint2*)&ldsA[idx] = u;
    }
    __syncthreads();
#pragma unroll
    for (int kk = 0; kk < 2; ++kk) {
      bf16x8 aF[4], bF[4];
#pragma unroll
      for (int mf = 0; mf < 4; ++mf) {
        int row = wm * 64 + mf * 16 + cl;
        int kl = kk * 32 + 8 * kh;
        aF[mf] = *(const bf16x8*)&ldsA[(row * 64 + kl) ^ ((row & 7) << 3)];
      }
#pragma unroll
      for (int nf = 0; nf < 4; ++nf) {
        int cc = wn * 64 + nf * 16 + cl;
        int k = k0 + kk * 32 + 8 * kh;
        bF[nf] = *(const bf16x8*)&ldsW[(cc * K + k) ^ ((cc & 7) << 3)];
      }
#pragma unroll
      for (int mf = 0; mf < 4; ++mf)
#pragma unroll
        for (int nf = 0; nf < 4; ++nf)
          acc[mf][nf] = __builtin_amdgcn_mfma_f32_16x16x32_bf16(aF[mf], bF[nf], acc[mf][nf], 0, 0, 0);
    }
    __syncthreads();
  }
#pragma unroll
  for (int mf = 0; mf < 4; ++mf)
#pragma unroll
    for (int nf = 0; nf < 4; ++nf)
#pragma unroll
      for (int j = 0; j < 4; ++j)
        Cg[(r0 + wm * 64 + mf * 16 + kh * 4 + j) * NSTR + s * 128 + wn * 64 + nf * 16 + cl] =
            acc[mf][nf][j];
}

// ---------------- recurrent scan (zero-flag sentinel exchange, pinned Wr) ----------------
// ex = 2 slots x [16 groups][16 rows][512 cols] bf16. Writer at step t -> slot t&1 with
// polarity P(t)=(t>>1)&1 in sign bits (data post-relu => sign-clear after strip).
// Reader at step t polls slot (t-1)&1 expecting P(t-1); stale/pristine data rejected
// (ABA prevented: each line's previous generation was observed by this block 2 steps ago).
__global__ __launch_bounds__(256, 1) void scan_kernel(
    const float* __restrict__ h0, const unsigned short* __restrict__ WrP,
    float* __restrict__ Hid, unsigned short* __restrict__ ex) {
  __shared__ unsigned short lt[16][136];  // own 16x128 slice, +8 pad
  const int tid = threadIdx.x, lane = tid & 63, wid = tid >> 6;
  const int g = blockIdx.x & 15, c = blockIdx.x >> 4;
  const int r0 = g * 16, c0 = c * 128;
  const int cl = lane & 15, kh = lane >> 4;
  const int wc = c0 + wid * 32;
  const int xr = tid >> 4, xcb = (tid & 15) * 8;  // export thread coords

  // Wr slice -> VGPRs via OPAQUE loads (compiler cannot sink/remat these into the loop).
  // ROTATED: index i holds k-block kk=(4c+i)&15, so own k-slices are i=0..3.
  i32x4 bwR0[16], bwR1[16];
  {
    const unsigned short* base = WrP + (size_t)c * 65536;
    const int cb0 = wid * 32 + cl, cb1 = cb0 + 16;
#pragma unroll
    for (int i = 0; i < 16; ++i) {
      int kk = (c * 4 + i) & 15;
      int k = kk * 32 + 8 * kh;
      bwR0[i] = load_b128_pin(base + (((cb0 << 9) | k) ^ ((cb0 & 7) << 3)));
      bwR1[i] = load_b128_pin(base + (((cb1 << 9) | k) ^ ((cb1 & 7) << 3)));
    }
    waitvm0();  // all 32 weight fragments resident before use
  }

  // ---------- t = 0 (peeled): all 16 A-fragments straight from h0 ----------
  float ai0[4], ai1[4];
#pragma unroll
  for (int j = 0; j < 4; ++j) {
    ai0[j] = Hid[(r0 + kh * 4 + j) * DLAT + wc + cl];
    ai1[j] = Hid[(r0 + kh * 4 + j) * DLAT + wc + 16 + cl];
  }
  f32x4 acc0 = {ai0[0], ai0[1], ai0[2], ai0[3]};
  f32x4 acc1 = {ai1[0], ai1[1], ai1[2], ai1[3]};
#pragma unroll
  for (int i = 0; i < 16; ++i) {
    int kk = (c * 4 + i) & 15;
    const float* hp = h0 + (size_t)(r0 + cl) * DLAT + kk * 32 + kh * 8;
    float4 a = *(const float4*)hp;
    float4 b = *(const float4*)(hp + 4);
    i32x4 w;
    w[0] = (int)pack2(a.x, a.y); w[1] = (int)pack2(a.z, a.w);
    w[2] = (int)pack2(b.x, b.y); w[3] = (int)pack2(b.z, b.w);
    bf16x8 aF = __builtin_bit_cast(bf16x8, w);
    acc0 = __builtin_amdgcn_mfma_f32_16x16x32_bf16(aF, __builtin_bit_cast(bf16x8, bwR0[i]), acc0, 0, 0, 0);
    acc1 = __builtin_amdgcn_mfma_f32_16x16x32_bf16(aF, __builtin_bit_cast(bf16x8, bwR1[i]), acc1, 0, 0, 0);
  }
  {
    float v0[4], v1[4];
#pragma unroll
    for (int j = 0; j < 4; ++j) {
      v0[j] = fmaxf(acc0[j], 0.f);
      v1[j] = fmaxf(acc1[j], 0.f);
      lt[kh * 4 + j][wid * 32 + cl] = (unsigned short)(f2bf(v0[j]) & 0x7fff);
      lt[kh * 4 + j][wid * 32 + 16 + cl] = (unsigned short)(f2bf(v1[j]) & 0x7fff);
    }
    __syncthreads();  // B2: transpose visible
    // export h_0 -> slot 0, polarity 0 (clean), fire-and-forget
    i32x4 w = *(const i32x4*)&lt[xr][xcb];
    store_b128_sc(ex + (size_t)g * 8192 + xr * 512 + c0 + xcb, w);
    // Hid f32 stores (fire-and-forget)
#pragma unroll
    for (int j = 0; j < 4; ++j) {
      Hid[(r0 + kh * 4 + j) * DLAT + wc + cl] = v0[j];
      Hid[(r0 + kh * 4 + j) * DLAT + wc + 16 + cl] = v1[j];
    }
    // prefetch ai for t=1
    const float* An = Hid + (size_t)1 * (BB * DLAT);
#pragma unroll
    for (int j = 0; j < 4; ++j) {
      ai0[j] = An[(r0 + kh * 4 + j) * DLAT + wc + cl];
      ai1[j] = An[(r0 + kh * 4 + j) * DLAT + wc + 16 + cl];
    }
  }

  // ---------- main loop t = 1 .. 511 ----------
  for (int t = 1; t < TT; ++t) {
    // own 4 k-slice fragments from LDS (clean)
    i32x4 of[4];
#pragma unroll
    for (int i = 0; i < 4; ++i) of[i] = *(const i32x4*)&lt[cl][i * 32 + kh * 8];
    __syncthreads();  // B1: of-reads done; lt may be overwritten below

    f32x4 a0 = {ai0[0], ai0[1], ai0[2], ai0[3]};
    f32x4 a1 = {ai1[0], ai1[1], ai1[2], ai1[3]};
#pragma unroll
    for (int i = 0; i < 4; ++i) {
      bf16x8 aF = __builtin_bit_cast(bf16x8, of[i]);
      a0 = __builtin_amdgcn_mfma_f32_16x16x32_bf16(aF, __builtin_bit_cast(bf16x8, bwR0[i]), a0, 0, 0, 0);
      a1 = __builtin_amdgcn_mfma_f32_16x16x32_bf16(aF, __builtin_bit_cast(bf16x8, bwR1[i]), a1, 0, 0, 0);
    }

    // poll 12 foreign chunks: slot (t-1)&1, expected polarity P(t-1)
    const unsigned short* exR = ex + (size_t)((t - 1) & 1) * 131072 + (size_t)g * 8192;
    const unsigned polr = (((t - 1) >> 1) & 1) ? 0x80008000u : 0u;
    i32x4 fa[12];
    for (;;) {
#pragma unroll
      for (int i = 0; i < 12; ++i) {
        int kk = (c * 4 + 4 + i) & 15;
        fa[i] = load_b128_sc(exR + cl * 512 + kk * 32 + kh * 8);
      }
      waitvm0();
      unsigned bad = 0;
#pragma unroll
      for (int i = 0; i < 12; ++i)
#pragma unroll
        for (int q = 0; q < 4; ++q)
          bad |= ((unsigned)fa[i][q] ^ polr) & 0x80008000u;
      if (!__any(bad)) break;
    }

    // prefetch ai for t+1 (after poll so it never gates this poll's vmcnt(0))
    float an0[4], an1[4];
    {
      int tn = (t < TT - 1) ? t + 1 : TT - 1;
      const float* An = Hid + (size_t)tn * (BB * DLAT);
#pragma unroll
      for (int j = 0; j < 4; ++j) {
        an0[j] = An[(r0 + kh * 4 + j) * DLAT + wc + cl];
        an1[j] = An[(r0 + kh * 4 + j) * DLAT + wc + 16 + cl];
      }
    }

    // foreign MFMAs (strip polarity/sign)
#pragma unroll
    for (int i = 0; i < 12; ++i) {
      i32x4 w = fa[i];
#pragma unroll
      for (int q = 0; q < 4; ++q) w[q] = (int)((unsigned)w[q] & 0x7fff7fffu);
      bf16x8 aF = __builtin_bit_cast(bf16x8, w);
      a0 = __builtin_amdgcn_mfma_f32_16x16x32_bf16(aF, __builtin_bit_cast(bf16x8, bwR0[4 + i]), a0, 0, 0, 0);
      a1 = __builtin_amdgcn_mfma_f32_16x16x32_bf16(aF, __builtin_bit_cast(bf16x8, bwR1[4 + i]), a1, 0, 0, 0);
    }

    // relu; clean write to lt
    float v0[4], v1[4];
#pragma unroll
    for (int j = 0; j < 4; ++j) {
      v0[j] = fmaxf(a0[j], 0.f);
      v1[j] = fmaxf(a1[j], 0.f);
      lt[kh * 4 + j][wid * 32 + cl] = (unsigned short)(f2bf(v0[j]) & 0x7fff);
      lt[kh * 4 + j][wid * 32 + 16 + cl] = (unsigned short)(f2bf(v1[j]) & 0x7fff);
    }
    __syncthreads();  // B2: transpose visible

    if (t < TT - 1) {  // export h_t -> slot t&1 with polarity P(t); fire-and-forget
      i32x4 w = *(const i32x4*)&lt[xr][xcb];
      const unsigned polw = ((t >> 1) & 1) ? 0x80008000u : 0u;
#pragma unroll
      for (int q = 0; q < 4; ++q) w[q] = (int)((unsigned)w[q] | polw);
      store_b128_sc(ex + (size_t)(t & 1) * 131072 + (size_t)g * 8192 + xr * 512 + c0 + xcb, w);
    }
    // Hid f32 stores (fire-and-forget)
    float* Ht = Hid + (size_t)t * (BB * DLAT);
#pragma unroll
    for (int j = 0; j < 4; ++j) {
      Ht[(r0 + kh * 4 + j) * DLAT + wc + cl] = v0[j];
      Ht[(r0 + kh * 4 + j) * DLAT + wc + 16 + cl] = v1[j];
    }
#pragma unroll
    for (int j = 0; j < 4; ++j) { ai0[j] = an0[j]; ai1[j] = an1[j]; }
  }
}

extern "C" void kernel_launch(void* const* d_in, const int* in_sizes, int n_in,
                              void* d_out, int out_size, void* d_ws, size_t ws_size,
                              hipStream_t stream) {
  const float* x  = (const float*)d_in[0];   // [T][B][256]
  const float* h0 = (const float*)d_in[1];   // [B][512]
  const float* Wh = (const float*)d_in[2];   // [768][512]
  const float* bh = (const float*)d_in[3];   // [512]
  const float* Wo = (const float*)d_in[4];   // [512][256]
  const float* bo = (const float*)d_in[5];   // [256]
  float* Out = (float*)d_out;                          // [T][B][256]
  float* Hid = Out + (size_t)TT * BB * DOUT;           // [T][B][512]

  unsigned short* ws_wx = (unsigned short*)d_ws;       // 131072 ushorts
  unsigned short* ws_wr = ws_wx + 131072;              // 262144
  unsigned short* ws_wo = ws_wr + 262144;              // 131072
  unsigned short* ex = ws_wo + 131072;                 // 2 x 131072 ushorts (512 KB)

  hipMemsetAsync(ex, 0xFF, 2 * 131072 * sizeof(unsigned short), stream);  // invalid sentinels
  prep_kernel<<<1024, 256, 0, stream>>>(Wh, Wo, ws_wx, ws_wr, ws_wo);
  gemm_bias<256, 512, 2><<<4096, 256, 0, stream>>>(x, ws_wx, bh, Hid);
  scan_kernel<<<64, 256, 0, stream>>>(h0, ws_wr, Hid, ex);
  gemm_bias<512, 256, 1><<<2048, 256, 0, stream>>>(Hid, ws_wo, bo, Out);
}